// Round 4
// baseline (795.064 us; speedup 1.0000x reference)
//
#include <hip/hip_runtime.h>
#include <stdint.h>

// ---------- types ----------
typedef __attribute__((ext_vector_type(8)))  __bf16 bf16x8;   // MFMA A/B frag (4 VGPRs)
typedef __attribute__((ext_vector_type(16))) float  f32x16;   // 32x32 MFMA C/D frag
typedef unsigned short u16;
typedef __attribute__((ext_vector_type(8))) unsigned short u16x8;

#define GLOBAL_AS __attribute__((address_space(1)))
#define LDS_AS    __attribute__((address_space(3)))

__device__ __forceinline__ void load_lds16(const void* g, void* l) {
    __builtin_amdgcn_global_load_lds((const GLOBAL_AS void*)g, (LDS_AS void*)l, 16, 0, 0);
}

__device__ __forceinline__ u16 f2bf(float f) {
    union { float f; uint32_t u; } v; v.f = f;
    uint32_t r = v.u + 0x7FFFu + ((v.u >> 16) & 1u);   // RNE
    return (u16)(r >> 16);
}
__device__ __forceinline__ float b2f(u16 b) {
    union { uint32_t u; float f; } v; v.u = ((uint32_t)b) << 16;
    return v.f;
}

// ---------- aux: fp32 -> bf16 convert with zero-padding ----------
__global__ void k_conv_pad(const float* __restrict__ in, u16* __restrict__ out,
                           int rIn, int cIn, int cOut, int total8) {
    int idx = blockIdx.x * blockDim.x + threadIdx.x;
    if (idx >= total8) return;
    int c8n = cOut >> 3;
    int r  = idx / c8n;
    int c0 = (idx - r * c8n) << 3;
    u16x8 o;
#pragma unroll
    for (int j = 0; j < 8; ++j) {
        int c = c0 + j;
        o[j] = (r < rIn && c < cIn) ? f2bf(in[(size_t)r * cIn + c]) : (u16)0;
    }
    *(u16x8*)(out + (size_t)r * cOut + c0) = o;
}

// ---------- aux: fp32 [kIn x nIn] -> bf16 transposed [nOut x kOut], zero-padded ----------
__global__ void k_transpose_conv(const float* __restrict__ in, u16* __restrict__ out,
                                 int kIn, int nIn, int kOut) {
    __shared__ float tile[32][33];
    int k0 = blockIdx.x * 32, n0 = blockIdx.y * 32;
    int tx = threadIdx.x, ty = threadIdx.y;   // block (32,8)
#pragma unroll
    for (int i = 0; i < 4; ++i) {
        int k = k0 + ty + i * 8, n = n0 + tx;
        tile[ty + i * 8][tx] = (k < kIn && n < nIn) ? in[(size_t)k * nIn + n] : 0.f;
    }
    __syncthreads();
#pragma unroll
    for (int i = 0; i < 4; ++i) {
        int n = n0 + ty + i * 8, k = k0 + tx;
        out[(size_t)n * kOut + k] = f2bf(tile[tx][ty + i * 8]);
    }
}

// ---------- main GEMM: C[M,N] = A[M,K] @ B[N,K]^T  (both bf16, K contiguous) ----------
// MODE 0: store bf16 with (row<mReal && col<nReal) guard (ldc = nReal)
// MODE 1: bf16 out = relu(acc + bias[col])
// MODE 2: fp32 out = acc + bias[col]
// 128x128 tile, BK=64, 4 waves each 64x64 as 2x2 of 32x32x16 MFMA.
// LDS cell (row r, chunk c of 16B) lives at slot c ^ (r&7) ^ 2*((r>>3)&3):
//   the (r&7) term spreads bank groups across consecutive-lane phases, the
//   2*((r>>3)&3) term spreads them across stride-8 lane phases (the R3 counter
//   showed +4 cyc/ds_read_b128 = 4-way grouping with the half-based swizzle).
// DMA writes stay contiguous; the global source column carries the swizzle.
template <int MODE>
__global__ __launch_bounds__(256) void k_gemm_bt(
    const u16* __restrict__ A, const u16* __restrict__ B,
    const u16* __restrict__ bias, void* __restrict__ Cv,
    int K, int ldc, int mReal, int nReal) {
    (void)bias;
    __shared__ __align__(16) char lds[32768];
    char* As = lds;            // [128 rows][8 chunks x 16B], swizzled
    char* Bs = lds + 16384;

    const int tid  = threadIdx.x;
    const int w    = tid >> 6, lane = tid & 63;
    const int l31  = lane & 31, hi = lane >> 5;
    const int wm   = (w & 1) * 64, wn = (w >> 1) * 64;
    const int bm   = blockIdx.y * 128, bn = blockIdx.x * 128;

    // staging: thread tid fetches global row = tid>>3 (+32t); slot s = tid&7 at
    // that row must hold chunk c = s ^ (r&7) ^ 2*((r>>3)&3); (r>>3)&3 == w for
    // all t (rows step by 32), so srcCol is t-independent.
    const int srcRow = tid >> 3;
    const int srcCol = (tid & 7) ^ (srcRow & 7) ^ (2 * w);
    const u16* aSrc = A + (size_t)(bm + srcRow) * K + (srcCol << 3);
    const u16* bSrc = B + (size_t)(bn + srcRow) * K + (srcCol << 3);
    char* aDst = As + ((tid & ~63) << 4);   // wave-uniform
    char* bDst = Bs + ((tid & ~63) << 4);

    f32x16 acc[2][2];
#pragma unroll
    for (int i = 0; i < 2; ++i)
#pragma unroll
        for (int j = 0; j < 2; ++j) acc[i][j] = (f32x16)(0.f);

    for (int k0 = 0; k0 < K; k0 += 64) {
#pragma unroll
        for (int t = 0; t < 4; ++t) {
            load_lds16(aSrc + (size_t)(t * 32) * K, aDst + t * 4096);
            load_lds16(bSrc + (size_t)(t * 32) * K, bDst + t * 4096);
        }
        aSrc += 64; bSrc += 64;
        __syncthreads();
#pragma unroll
        for (int ks = 0; ks < 4; ++ks) {
            // A-frag (32x32x16): lane holds A[m=l31][k = ks*16 + hi*8 .. +8]
            // chunk c = ks*2+hi at row l31 (wm, i*32 only touch bits >=5)
            const int swz = (((ks * 2 + hi) ^ (l31 & 7) ^ (2 * ((l31 >> 3) & 3))) << 4);
            bf16x8 af[2], bfr[2];
#pragma unroll
            for (int i = 0; i < 2; ++i) {
                af[i]  = *(const bf16x8*)(As + (wm + i * 32 + l31) * 128 + swz);
                bfr[i] = *(const bf16x8*)(Bs + (wn + i * 32 + l31) * 128 + swz);
            }
#pragma unroll
            for (int mi = 0; mi < 2; ++mi)
#pragma unroll
                for (int ni = 0; ni < 2; ++ni)
                    acc[mi][ni] = __builtin_amdgcn_mfma_f32_32x32x16_bf16(
                        af[mi], bfr[ni], acc[mi][ni], 0, 0, 0);
        }
        __syncthreads();
    }

    // epilogue. 32x32 C/D layout: col = lane&31, row = (reg&3) + 8*(reg>>2) + 4*hi
    // (m74/m101-verified)
    float bv[2];
    if (MODE >= 1) {
#pragma unroll
        for (int ni = 0; ni < 2; ++ni) bv[ni] = b2f(bias[bn + wn + ni * 32 + l31]);
    }
#pragma unroll
    for (int mi = 0; mi < 2; ++mi) {
#pragma unroll
        for (int reg = 0; reg < 16; ++reg) {
            int row = bm + wm + mi * 32 + (reg & 3) + 8 * (reg >> 2) + 4 * hi;
#pragma unroll
            for (int ni = 0; ni < 2; ++ni) {
                int col = bn + wn + ni * 32 + l31;
                float v = acc[mi][ni][reg];
                if (MODE == 0) {
                    if (row < mReal && col < nReal)
                        ((u16*)Cv)[(size_t)row * ldc + col] = f2bf(v);
                } else if (MODE == 1) {
                    v += bv[ni];
                    v = v > 0.f ? v : 0.f;
                    ((u16*)Cv)[(size_t)row * ldc + col] = f2bf(v);
                } else {
                    ((float*)Cv)[(size_t)row * ldc + col] = v + bv[ni];
                }
            }
        }
    }
}

// ---------- launch ----------
// Sizes: D_IN=2048, D_H=4096, D_OUT=2048, B=4096; SIZE_N=5794, SIZE_M=2897
// Padded GEMM0 dims: M=N=5888 (46*128), K=2944 (46*64)
// Vf flat unpack offsets (elems):
//   W1 @ 0, b1 @ 8388608, W2 @ 8392704, b2 @ 25169920, W3 @ 25174016, b3 @ 33562624
extern "C" void kernel_launch(void* const* d_in, const int* in_sizes, int n_in,
                              void* d_out, int out_size, void* d_ws, size_t ws_size,
                              hipStream_t stream) {
    (void)in_sizes; (void)n_in; (void)out_size; (void)ws_size;
    const float* x  = (const float*)d_in[0];
    const float* V1 = (const float*)d_in[1];
    const float* V2 = (const float*)d_in[2];

    char* ws = (char*)d_ws;
    u16* Vf   = (u16*)(ws);                            // 5794*5794 bf16 -> 67,140,872 B
    u16* V1b  = (u16*)(ws + 67141120);                 // [5888 x 2944] bf16 = 34,668,544 B
    u16* V2bT = (u16*)(ws + 67141120 + 34668544);      // [5888 x 2944] bf16
    u16* Xb   = (u16*)(ws + 67141120 + 2 * 34668544);  // [4096 x 2048] bf16
    u16* H1   = V1b;   // dead after GEMM0
    u16* H2   = V2bT;

    k_conv_pad<<<8464, 256, 0, stream>>>(V1, V1b, 5794, 2897, 2944, 5888 * 2944 / 8);
    k_transpose_conv<<<dim3(92, 184), dim3(32, 8), 0, stream>>>(V2, V2bT, 2897, 5794, 2944);
    k_conv_pad<<<4096, 256, 0, stream>>>(x, Xb, 4096, 2048, 2048, 4096 * 2048 / 8);

    // G0: Vf = V1 @ V2  (padded 5888x5888x2944, guarded store into flat [5794x5794])
    k_gemm_bt<0><<<dim3(46, 46), 256, 0, stream>>>(V1b, V2bT, nullptr, Vf,
                                                   2944, 5794, 5794, 5794);
    // G1: H1 = relu(Xb @ W1^T + b1)   [4096x4096], K=2048
    k_gemm_bt<1><<<dim3(32, 32), 256, 0, stream>>>(Xb, Vf + 0, Vf + 8388608, H1,
                                                   2048, 4096, 4096, 4096);
    // G2: H2 = relu(H1 @ W2^T + b2)   [4096x4096], K=4096
    k_gemm_bt<1><<<dim3(32, 32), 256, 0, stream>>>(H1, Vf + 8392704, Vf + 25169920, H2,
                                                   4096, 4096, 4096, 4096);
    // G3: out = H2 @ W3^T + b3        [4096x2048] fp32, K=4096
    k_gemm_bt<2><<<dim3(16, 32), 256, 0, stream>>>(H2, Vf + 25174016, Vf + 33562624, d_out,
                                                   4096, 2048, 4096, 2048);
}

// Round 5
// 781.030 us; speedup vs baseline: 1.0180x; 1.0180x over previous
//
#include <hip/hip_runtime.h>
#include <stdint.h>

// ---------- types ----------
typedef __attribute__((ext_vector_type(8)))  __bf16 bf16x8;   // MFMA A/B frag (4 VGPRs)
typedef __attribute__((ext_vector_type(16))) float  f32x16;   // 32x32 MFMA C/D frag
typedef unsigned short u16;
typedef __attribute__((ext_vector_type(8))) unsigned short u16x8;

#define GLOBAL_AS __attribute__((address_space(1)))
#define LDS_AS    __attribute__((address_space(3)))

__device__ __forceinline__ void load_lds16(const void* g, void* l) {
    __builtin_amdgcn_global_load_lds((const GLOBAL_AS void*)g, (LDS_AS void*)l, 16, 0, 0);
}

__device__ __forceinline__ u16 f2bf(float f) {
    union { float f; uint32_t u; } v; v.f = f;
    uint32_t r = v.u + 0x7FFFu + ((v.u >> 16) & 1u);   // RNE
    return (u16)(r >> 16);
}
__device__ __forceinline__ float b2f(u16 b) {
    union { uint32_t u; float f; } v; v.u = ((uint32_t)b) << 16;
    return v.f;
}

// ---------- aux: fp32 -> bf16 convert with zero-padding ----------
__global__ void k_conv_pad(const float* __restrict__ in, u16* __restrict__ out,
                           int rIn, int cIn, int cOut, int total8) {
    int idx = blockIdx.x * blockDim.x + threadIdx.x;
    if (idx >= total8) return;
    int c8n = cOut >> 3;
    int r  = idx / c8n;
    int c0 = (idx - r * c8n) << 3;
    u16x8 o;
#pragma unroll
    for (int j = 0; j < 8; ++j) {
        int c = c0 + j;
        o[j] = (r < rIn && c < cIn) ? f2bf(in[(size_t)r * cIn + c]) : (u16)0;
    }
    *(u16x8*)(out + (size_t)r * cOut + c0) = o;
}

// ---------- aux: fp32 [kIn x nIn] -> bf16 transposed [nOut x kOut], zero-padded ----------
__global__ void k_transpose_conv(const float* __restrict__ in, u16* __restrict__ out,
                                 int kIn, int nIn, int kOut) {
    __shared__ float tile[32][33];
    int k0 = blockIdx.x * 32, n0 = blockIdx.y * 32;
    int tx = threadIdx.x, ty = threadIdx.y;   // block (32,8)
#pragma unroll
    for (int i = 0; i < 4; ++i) {
        int k = k0 + ty + i * 8, n = n0 + tx;
        tile[ty + i * 8][tx] = (k < kIn && n < nIn) ? in[(size_t)k * nIn + n] : 0.f;
    }
    __syncthreads();
#pragma unroll
    for (int i = 0; i < 4; ++i) {
        int n = n0 + ty + i * 8, k = k0 + tx;
        out[(size_t)n * kOut + k] = f2bf(tile[tx][ty + i * 8]);
    }
}

// ---------- main GEMM: C[M,N] = A[M,K] @ B[N,K]^T  (both bf16, K contiguous) ----------
// MODE 0: store bf16 with (row<mReal && col<nReal) guard (ldc = nReal)
// MODE 1: bf16 out = relu(acc + bias[col])
// MODE 2: fp32 out = acc + bias[col]
// 128x128 tile, BK=64, 4 waves each 64x64 as 2x2 of 32x32x16 MFMA.
// LDS cell (row r, chunk c of 16B) at slot c ^ (r&7) (R2-proven family; the
// residual 4 cyc/read conflict is invariant under re-swizzling — R3 vs R4
// identical counters — so treated as shape-structural and accepted).
// __launch_bounds__(256,4): force <=128 unified VGPR+AGPR -> 4 waves/SIMD
// (R4 showed 132 regs = 3 waves/SIMD = 30% occupancy; the kernel is
// latency/barrier-bound with all pipes <40%, so co-residency is the lever).
template <int MODE>
__global__ __launch_bounds__(256, 4) void k_gemm_bt(
    const u16* __restrict__ A, const u16* __restrict__ B,
    const u16* __restrict__ bias, void* __restrict__ Cv,
    int K, int ldc, int mReal, int nReal) {
    (void)bias;
    __shared__ __align__(16) char lds[32768];
    char* As = lds;            // [128 rows][8 chunks x 16B], swizzled
    char* Bs = lds + 16384;

    const int tid  = threadIdx.x;
    const int w    = tid >> 6, lane = tid & 63;
    const int l31  = lane & 31, hi = lane >> 5;
    const int wm   = (w & 1) * 64, wn = (w >> 1) * 64;
    const int bm   = blockIdx.y * 128, bn = blockIdx.x * 128;

    // staging: thread tid fetches global (row = tid>>3 + 32t, chunk = (tid&7)^(row&7))
    const int srcRow = tid >> 3;
    const int srcCol = (tid & 7) ^ (srcRow & 7);
    const u16* aSrc = A + (size_t)(bm + srcRow) * K + (srcCol << 3);
    const u16* bSrc = B + (size_t)(bn + srcRow) * K + (srcCol << 3);
    char* aDst = As + ((tid & ~63) << 4);   // wave-uniform
    char* bDst = Bs + ((tid & ~63) << 4);

    // precomputed LDS row byte-offsets (swz added per ks)
    const int aRow0 = (wm + l31) * 128;
    const int aRow1 = (wm + 32 + l31) * 128;
    const int bRow0 = (wn + l31) * 128;
    const int bRow1 = (wn + 32 + l31) * 128;

    f32x16 acc[2][2];
#pragma unroll
    for (int i = 0; i < 2; ++i)
#pragma unroll
        for (int j = 0; j < 2; ++j) acc[i][j] = (f32x16)(0.f);

    for (int k0 = 0; k0 < K; k0 += 64) {
#pragma unroll
        for (int t = 0; t < 4; ++t) {
            load_lds16(aSrc + (size_t)(t * 32) * K, aDst + t * 4096);
            load_lds16(bSrc + (size_t)(t * 32) * K, bDst + t * 4096);
        }
        aSrc += 64; bSrc += 64;
        __syncthreads();
#pragma unroll
        for (int ks = 0; ks < 4; ++ks) {
            // A-frag (32x32x16): lane holds A[m=l31][k = ks*16 + hi*8 .. +8]
            const int swz = (((ks * 2 + hi) ^ (l31 & 7)) << 4);
            bf16x8 af[2], bfr[2];
            af[0]  = *(const bf16x8*)(As + aRow0 + swz);
            af[1]  = *(const bf16x8*)(As + aRow1 + swz);
            bfr[0] = *(const bf16x8*)(Bs + bRow0 + swz);
            bfr[1] = *(const bf16x8*)(Bs + bRow1 + swz);
#pragma unroll
            for (int mi = 0; mi < 2; ++mi)
#pragma unroll
                for (int ni = 0; ni < 2; ++ni)
                    acc[mi][ni] = __builtin_amdgcn_mfma_f32_32x32x16_bf16(
                        af[mi], bfr[ni], acc[mi][ni], 0, 0, 0);
        }
        __syncthreads();
    }

    // epilogue. 32x32 C/D layout: col = lane&31, row = (reg&3) + 8*(reg>>2) + 4*hi
    // (m74/m101-verified)
    float bv[2];
    if (MODE >= 1) {
#pragma unroll
        for (int ni = 0; ni < 2; ++ni) bv[ni] = b2f(bias[bn + wn + ni * 32 + l31]);
    }
#pragma unroll
    for (int mi = 0; mi < 2; ++mi) {
#pragma unroll
        for (int reg = 0; reg < 16; ++reg) {
            int row = bm + wm + mi * 32 + (reg & 3) + 8 * (reg >> 2) + 4 * hi;
#pragma unroll
            for (int ni = 0; ni < 2; ++ni) {
                int col = bn + wn + ni * 32 + l31;
                float v = acc[mi][ni][reg];
                if (MODE == 0) {
                    if (row < mReal && col < nReal)
                        ((u16*)Cv)[(size_t)row * ldc + col] = f2bf(v);
                } else if (MODE == 1) {
                    v += bv[ni];
                    v = v > 0.f ? v : 0.f;
                    ((u16*)Cv)[(size_t)row * ldc + col] = f2bf(v);
                } else {
                    ((float*)Cv)[(size_t)row * ldc + col] = v + bv[ni];
                }
            }
        }
    }
}

// ---------- launch ----------
// Sizes: D_IN=2048, D_H=4096, D_OUT=2048, B=4096; SIZE_N=5794, SIZE_M=2897
// Padded GEMM0 dims: M=N=5888 (46*128), K=2944 (46*64)
// Vf flat unpack offsets (elems):
//   W1 @ 0, b1 @ 8388608, W2 @ 8392704, b2 @ 25169920, W3 @ 25174016, b3 @ 33562624
extern "C" void kernel_launch(void* const* d_in, const int* in_sizes, int n_in,
                              void* d_out, int out_size, void* d_ws, size_t ws_size,
                              hipStream_t stream) {
    (void)in_sizes; (void)n_in; (void)out_size; (void)ws_size;
    const float* x  = (const float*)d_in[0];
    const float* V1 = (const float*)d_in[1];
    const float* V2 = (const float*)d_in[2];

    char* ws = (char*)d_ws;
    u16* Vf   = (u16*)(ws);                            // 5794*5794 bf16 -> 67,140,872 B
    u16* V1b  = (u16*)(ws + 67141120);                 // [5888 x 2944] bf16 = 34,668,544 B
    u16* V2bT = (u16*)(ws + 67141120 + 34668544);      // [5888 x 2944] bf16
    u16* Xb   = (u16*)(ws + 67141120 + 2 * 34668544);  // [4096 x 2048] bf16
    u16* H1   = V1b;   // dead after GEMM0
    u16* H2   = V2bT;

    k_conv_pad<<<8464, 256, 0, stream>>>(V1, V1b, 5794, 2897, 2944, 5888 * 2944 / 8);
    k_transpose_conv<<<dim3(92, 184), dim3(32, 8), 0, stream>>>(V2, V2bT, 2897, 5794, 2944);
    k_conv_pad<<<4096, 256, 0, stream>>>(x, Xb, 4096, 2048, 2048, 4096 * 2048 / 8);

    // G0: Vf = V1 @ V2  (padded 5888x5888x2944, guarded store into flat [5794x5794])
    k_gemm_bt<0><<<dim3(46, 46), 256, 0, stream>>>(V1b, V2bT, nullptr, Vf,
                                                   2944, 5794, 5794, 5794);
    // G1: H1 = relu(Xb @ W1^T + b1)   [4096x4096], K=2048
    k_gemm_bt<1><<<dim3(32, 32), 256, 0, stream>>>(Xb, Vf + 0, Vf + 8388608, H1,
                                                   2048, 4096, 4096, 4096);
    // G2: H2 = relu(H1 @ W2^T + b2)   [4096x4096], K=4096
    k_gemm_bt<1><<<dim3(32, 32), 256, 0, stream>>>(H1, Vf + 8392704, Vf + 25169920, H2,
                                                   4096, 4096, 4096, 4096);
    // G3: out = H2 @ W3^T + b3        [4096x2048] fp32, K=4096
    k_gemm_bt<2><<<dim3(16, 32), 256, 0, stream>>>(H2, Vf + 25174016, Vf + 33562624, d_out,
                                                   4096, 2048, 4096, 2048);
}